// Round 14
// baseline (483.088 us; speedup 1.0000x reference)
//
#include <hip/hip_runtime.h>
#include <math.h>
#include <float.h>

#define BN_EPS 1e-5f

__device__ __forceinline__ float bn_apply(float y, float g, float b, float m, float v) {
  float s = g / sqrtf(v + BN_EPS);
  return y * s + (b - m * s);
}

// zero the border pixels of padded NCHW A [512][16][34][34]
__global__ void k_pad0(float* __restrict__ A) {
  int n = blockIdx.x, t = threadIdx.x;
  float* ab = A + n * 18496;
  for (int idx = t; idx < 2112; idx += 256) {   // 16 ch * 132 border px
    int ch = idx / 132, b = idx - ch * 132;
    int r, c;
    if (b < 34)       { r = 0;      c = b; }
    else if (b < 68)  { r = 33;     c = b - 34; }
    else if (b < 100) { r = b - 67; c = 0; }    // rows 1..32
    else              { r = b - 99; c = 33; }
    ab[ch * 1156 + r * 34 + c] = 0.0f;
  }
}

// reorder conv2 weights: wr2[og*1024 + i*64 + k*4 + oo] = w[(og*4+oo)*256 + i*16 + k]
__global__ void k_wr2(const float* __restrict__ w, float* __restrict__ wr2) {
  int idx = blockIdx.x * 256 + threadIdx.x;   // 4096
  int og = idx >> 10, rem = idx & 1023;
  int i = rem >> 6, r2 = rem & 63;
  int k = r2 >> 2, oo = r2 & 3;
  wr2[idx] = w[(og * 4 + oo) * 256 + i * 16 + k];
}

// ---------------- encoder ----------------
// conv1 v2: [512,1,64,64] -> padded NCHW A [512,16,34,34] interior, k4 s2 p1 + bn + relu.
// Block per image: input staged in zero-padded 66x66 LDS (no masked loads),
// weights + folded BN consts in LDS. 4 outputs/thread, 1024 FMA each.
__global__ void __launch_bounds__(256) k_conv1(const float* __restrict__ x,
                        const float* __restrict__ w, const float* __restrict__ bias,
                        const float* __restrict__ g, const float* __restrict__ bb,
                        const float* __restrict__ bm, const float* __restrict__ bv,
                        float* __restrict__ A) {
  __shared__ float xs[66 * 66];
  __shared__ float wsh[256];
  __shared__ float k1a[16], k1b[16];
  int n = blockIdx.x, t = threadIdx.x;
  // zero border cells (260)
  for (int i = t; i < 260; i += 256) {
    int r, c;
    if (i < 66)       { r = 0;       c = i; }
    else if (i < 132) { r = 65;      c = i - 66; }
    else if (i < 196) { r = i - 131; c = 0; }     // rows 1..64
    else              { r = i - 195; c = 65; }
    xs[r * 66 + c] = 0.0f;
  }
  // stage interior: 64 rows x 16 float4
  {
    const float4* xv = (const float4*)(x + n * 4096);
    for (int i = t; i < 1024; i += 256) {
      int iy = i >> 4, qq = i & 15;
      float4 v = xv[i];
      float* dst = &xs[(iy + 1) * 66 + 1 + qq * 4];
      dst[0] = v.x; dst[1] = v.y; dst[2] = v.z; dst[3] = v.w;
    }
  }
  if (t < 256) wsh[t] = w[t];
  if (t < 16) {
    float s = g[t] / sqrtf(bv[t] + BN_EPS);
    k1a[t] = s;
    k1b[t] = bias[t] * s + (bb[t] - bm[t] * s);
  }
  __syncthreads();
  float* An = A + n * 18496;
#pragma unroll
  for (int qq = 0; qq < 4; ++qq) {
    int q = t + 256 * qq;                  // 0..1023
    int yo = q >> 5, xo = q & 31;
    const float* base = &xs[(2 * yo) * 66 + 2 * xo];   // padded: tap = base[ky*66+kx]
    float p[16];
#pragma unroll
    for (int ky = 0; ky < 4; ++ky)
#pragma unroll
      for (int kx = 0; kx < 4; ++kx)
        p[ky * 4 + kx] = base[ky * 66 + kx];
    float* ob = An + (yo + 1) * 34 + (xo + 1);
#pragma unroll
    for (int o = 0; o < 16; ++o) {
      float acc = 0.0f;
#pragma unroll
      for (int k = 0; k < 16; ++k) acc = fmaf(p[k], wsh[o * 16 + k], acc);
      ob[o * 1156] = fmaxf(acc * k1a[o] + k1b[o], 0.0f);
    }
  }
}

// conv2 v8 (kept from R13 — proven): padded NCHW in, thread=(pixel, og of 4 och).
__global__ void __launch_bounds__(256) k_conv2(const float* __restrict__ A,
                        const float* __restrict__ wr2, const float* __restrict__ bias,
                        const float* __restrict__ g, const float* __restrict__ bb,
                        const float* __restrict__ bm, const float* __restrict__ bv,
                        float* __restrict__ out) {
  int t = threadIdx.x;
  int lane = t & 63;
  int og = __builtin_amdgcn_readfirstlane(t >> 6);   // 0..3
  int idx = blockIdx.x * 64 + lane;                  // [0, 131072) = n*256 + p
  int n = idx >> 8, p = idx & 255;
  int yo = p >> 4, xo = p & 15;
  const float* Ab = A + n * 18496 + (2 * yo) * 34 + 2 * xo;
  const float* wb = wr2 + og * 1024;
  float acc[4];
#pragma unroll
  for (int oo = 0; oo < 4; ++oo) acc[oo] = bias[og * 4 + oo];
  for (int i = 0; i < 16; ++i) {
    const float* ch = Ab + i * 1156;
    float pv[16];
#pragma unroll
    for (int ky = 0; ky < 4; ++ky) {
      float2 a = *(const float2*)(ch + ky * 34);
      float2 b = *(const float2*)(ch + ky * 34 + 2);
      pv[ky * 4 + 0] = a.x; pv[ky * 4 + 1] = a.y;
      pv[ky * 4 + 2] = b.x; pv[ky * 4 + 3] = b.y;
    }
    const float* wt = wb + i * 64;   // [k][oo] contiguous, wave-uniform -> s_load
#pragma unroll
    for (int k = 0; k < 16; ++k) {
#pragma unroll
      for (int oo = 0; oo < 4; ++oo)
        acc[oo] = fmaf(pv[k], wt[k * 4 + oo], acc[oo]);
    }
  }
  float* ob = out + n * 4096 + p;
#pragma unroll
  for (int oo = 0; oo < 4; ++oo) {
    int o = og * 4 + oo;
    float s = g[o] / sqrtf(bv[o] + BN_EPS);
    float sh = bb[o] - bm[o] * s;
    ob[o * 256] = fmaxf(acc[oo] * s + sh, 0.0f);
  }
}

// conv3 + conv4 FUSED. Grid 1024 = (n, half).
__global__ void __launch_bounds__(256) k_c34(const float* __restrict__ in,
    const float* __restrict__ w3, const float* __restrict__ b3,
    const float* __restrict__ g3, const float* __restrict__ bb3,
    const float* __restrict__ bm3, const float* __restrict__ bv3,
    const float* __restrict__ w4, const float* __restrict__ b4,
    const float* __restrict__ g4, const float* __restrict__ bb4,
    const float* __restrict__ bm4, const float* __restrict__ bv4,
    float* __restrict__ hl) {
  __shared__ float xin[4096];
  __shared__ float w3s[1024];
  __shared__ float c3s[16 * 81];
  __shared__ float k3a[16], k3b[16];
  __shared__ float k4a[128], k4b[128];
  int bx = blockIdx.x;
  int n = bx >> 1, half = bx & 1;
  int t = threadIdx.x;
  {
    const float4* iv = (const float4*)(in + n * 4096);
    float4* xv = (float4*)xin;
#pragma unroll
    for (int q = 0; q < 4; ++q) xv[t + 256 * q] = iv[t + 256 * q];
    for (int i = t; i < 1024; i += 256) w3s[i] = w3[i];
  }
  if (t < 16) {
    float s = g3[t] / sqrtf(bv3[t] + BN_EPS);
    k3a[t] = s;
    k3b[t] = b3[t] * s + (bb3[t] - bm3[t] * s);
  } else if (t >= 64 && t < 192) {
    int o = t - 64;
    float s = g4[o] / sqrtf(bv4[o] + BN_EPS);
    k4a[o] = s;
    k4b[o] = b4[o] * s + (bb4[o] - bm4[o] * s);
  }
  __syncthreads();
  for (int idx = t; idx < 1296; idx += 256) {
    int o = idx / 81, p = idx - o * 81;
    int yo = p / 9, xo = p - yo * 9;
    int iy0 = 2 * yo - 1, ix0 = 2 * xo - 1;
    bool ytop = iy0 >= 0, ybot = iy0 + 1 < 16;
    bool xlft = ix0 >= 0, xrgt = ix0 + 1 < 16;
    int iyt = ytop ? iy0 : 0, iyb = ybot ? iy0 + 1 : 15;
    int ixl = xlft ? ix0 : 0, ixr = xrgt ? ix0 + 1 : 15;
    float acc = 0.0f;
#pragma unroll
    for (int i = 0; i < 16; ++i) {
      const float* ch = xin + i * 256;
      float p0 = (ytop & xlft) ? ch[iyt * 16 + ixl] : 0.0f;
      float p1 = (ytop & xrgt) ? ch[iyt * 16 + ixr] : 0.0f;
      float p2 = (ybot & xlft) ? ch[iyb * 16 + ixl] : 0.0f;
      float p3 = (ybot & xrgt) ? ch[iyb * 16 + ixr] : 0.0f;
      float4 wv = *(const float4*)&w3s[(o * 16 + i) * 4];
      acc += p0 * wv.x + p1 * wv.y + p2 * wv.z + p3 * wv.w;
    }
    c3s[idx] = fmaxf(acc * k3a[o] + k3b[o], 0.0f);
  }
  __syncthreads();
  int lane = t & 63;
  int og = __builtin_amdgcn_readfirstlane(t >> 6);   // 0..3
  int o0 = half * 64 + og * 16;
  float* ob = hl + n * 10368;
#pragma unroll
  for (int pass = 0; pass < 2; ++pass) {
    int p = pass * 64 + lane;
    bool ok = p < 81; int pc = ok ? p : 80;
    float acc[16];
#pragma unroll
    for (int oo = 0; oo < 16; ++oo) acc[oo] = 0.0f;
#pragma unroll
    for (int i = 0; i < 16; ++i) {
      float v = c3s[i * 81 + pc];
#pragma unroll
      for (int oo = 0; oo < 16; ++oo)
        acc[oo] = fmaf(v, w4[(o0 + oo) * 16 + i], acc[oo]);
    }
    if (ok) {
#pragma unroll
      for (int oo = 0; oo < 16; ++oo) {
        int o = o0 + oo;
        ob[o * 81 + p] = fmaxf(acc[oo] * k4a[o] + k4b[o], 0.0f);
      }
    }
  }
}

// fc21+fc22 fused split-K GEMM v4 (register double-buffer prefetch).
__global__ void __launch_bounds__(256) k_gemm1(const float* __restrict__ hl,
                                               const float* __restrict__ w21,
                                               const float* __restrict__ w22,
                                               float* __restrict__ part) {
  __shared__ __align__(16) float hs[27 * 68];
  __shared__ __align__(16) float wsh[27 * 128];
  int kc = blockIdx.x, nt = blockIdx.y, t = threadIdx.x;
  int n0 = nt * 64, k0 = kc * 162;
  int jg = t & 31, ng = t >> 5;
  float acc[8][4];
#pragma unroll
  for (int i = 0; i < 8; ++i)
#pragma unroll
    for (int q = 0; q < 4; ++q) acc[i][q] = 0.0f;
  float ph[7], pw[14];
  {
    int ks = k0;
#pragma unroll
    for (int q = 0; q < 7; ++q) {
      int idx = t + q * 256;
      if (idx < 1728) { int nr = idx / 27, kk = idx - nr * 27;
        ph[q] = hl[(n0 + nr) * 10368 + ks + kk]; }
    }
#pragma unroll
    for (int q = 0; q < 14; ++q) {
      int idx = t + q * 256;
      if (idx < 3456) { int r = idx >> 7, c = idx & 127;
        pw[q] = (c < 64) ? w21[(ks + r) * 64 + c] : w22[(ks + r) * 64 + (c - 64)]; }
    }
  }
  for (int s = 0; s < 6; ++s) {
    __syncthreads();
#pragma unroll
    for (int q = 0; q < 7; ++q) {
      int idx = t + q * 256;
      if (idx < 1728) { int nr = idx / 27, kk = idx - nr * 27; hs[kk * 68 + nr] = ph[q]; }
    }
#pragma unroll
    for (int q = 0; q < 14; ++q) {
      int idx = t + q * 256;
      if (idx < 3456) wsh[idx] = pw[q];
    }
    __syncthreads();
    if (s < 5) {
      int ks = k0 + (s + 1) * 27;
#pragma unroll
      for (int q = 0; q < 7; ++q) {
        int idx = t + q * 256;
        if (idx < 1728) { int nr = idx / 27, kk = idx - nr * 27;
          ph[q] = hl[(n0 + nr) * 10368 + ks + kk]; }
      }
#pragma unroll
      for (int q = 0; q < 14; ++q) {
        int idx = t + q * 256;
        if (idx < 3456) { int r = idx >> 7, c = idx & 127;
          pw[q] = (c < 64) ? w21[(ks + r) * 64 + c] : w22[(ks + r) * 64 + (c - 64)]; }
      }
    }
#pragma unroll 9
    for (int kk = 0; kk < 27; ++kk) {
      float4 h0 = *(const float4*)&hs[kk * 68 + ng * 8];
      float4 h1 = *(const float4*)&hs[kk * 68 + ng * 8 + 4];
      float4 wv = *(const float4*)&wsh[kk * 128 + jg * 4];
      float hv[8] = {h0.x, h0.y, h0.z, h0.w, h1.x, h1.y, h1.z, h1.w};
#pragma unroll
      for (int i = 0; i < 8; ++i) {
        acc[i][0] = fmaf(hv[i], wv.x, acc[i][0]);
        acc[i][1] = fmaf(hv[i], wv.y, acc[i][1]);
        acc[i][2] = fmaf(hv[i], wv.z, acc[i][2]);
        acc[i][3] = fmaf(hv[i], wv.w, acc[i][3]);
      }
    }
  }
#pragma unroll
  for (int i = 0; i < 8; ++i) {
    int n = n0 + ng * 8 + i;
    *(float4*)&part[(size_t)(kc * 512 + n) * 128 + jg * 4] =
        make_float4(acc[i][0], acc[i][1], acc[i][2], acc[i][3]);
  }
}

// reduce partials + bias -> z, mu, logvar
__global__ void k_fc_red(const float* __restrict__ part, const float* __restrict__ b21,
                         const float* __restrict__ b22, float* __restrict__ z,
                         float* __restrict__ mu, float* __restrict__ lv) {
  int t = blockIdx.x * 256 + threadIdx.x;   // 65536
  int j = t & 127, n = t >> 7;
  float s = 0.0f;
  for (int kc = 0; kc < 64; ++kc) s += part[(size_t)(kc * 512 + n) * 128 + j];
  if (j < 64) { float r = s + b21[j]; z[n * 64 + j] = r; mu[n * 64 + j] = r; }
  else        { lv[n * 64 + (j - 64)] = s + b22[j - 64]; }
}

// fc3 + relu: [512,64] @ [64,10368]. grid (81, 16 n-tiles), block 128 (m).
__global__ void k_fc3(const float* __restrict__ z, const float* __restrict__ w,
                      const float* __restrict__ b, float* __restrict__ E) {
  int m = blockIdx.x * 128 + threadIdx.x;
  int n0 = blockIdx.y * 32;
  float acc[32];
#pragma unroll
  for (int nn = 0; nn < 32; ++nn) acc[nn] = 0.0f;
  for (int j = 0; j < 64; ++j) {
    float wv = w[j * 10368 + m];
    const float* zb = z + n0 * 64 + j;
#pragma unroll
    for (int nn = 0; nn < 32; ++nn) acc[nn] += zb[nn * 64] * wv;
  }
  float bvv = b[m];
  float* Eb = E + n0 * 10368 + m;
#pragma unroll
  for (int nn = 0; nn < 32; ++nn) Eb[nn * 10368] = fmaxf(acc[nn] + bvv, 0.0f);
}

// fused cw1(128->32)+bn+relu + cw2(32->32). Block per image, wave-uniform o-group.
__global__ void __launch_bounds__(256) k_cw(const float* __restrict__ E,
                     const float* __restrict__ w1, const float* __restrict__ b1,
                     const float* __restrict__ g, const float* __restrict__ bb,
                     const float* __restrict__ bm, const float* __restrict__ bv,
                     const float* __restrict__ w2, const float* __restrict__ b2,
                     float* __restrict__ zex, float* __restrict__ zt) {
  __shared__ float ze_s[2592];
  int n = blockIdx.x, t = threadIdx.x;
  int lane = t & 63;
  int o0 = __builtin_amdgcn_readfirstlane(t >> 6) * 8;   // 0,8,16,24
  const float* co = E + n * 10368;
#pragma unroll
  for (int pass = 0; pass < 2; ++pass) {
    int p = pass * 64 + lane;
    bool ok = p < 81; int pc = ok ? p : 80;
    float acc[8];
#pragma unroll
    for (int oo = 0; oo < 8; ++oo) acc[oo] = b1[o0 + oo];
    for (int i = 0; i < 128; ++i) {
      float v = co[i * 81 + pc];
#pragma unroll
      for (int oo = 0; oo < 8; ++oo)
        acc[oo] = fmaf(v, w1[i * 32 + o0 + oo], acc[oo]);
    }
#pragma unroll
    for (int oo = 0; oo < 8; ++oo) {
      int o = o0 + oo;
      float r = bn_apply(acc[oo], g[o], bb[o], bm[o], bv[o]);
      if (ok) ze_s[o * 81 + p] = fmaxf(r, 0.0f);
    }
  }
  __syncthreads();
  float* zb = zex + n * 2592;
  float* ztb = zt + n * 81 * 32;
#pragma unroll
  for (int pass = 0; pass < 2; ++pass) {
    int p = pass * 64 + lane;
    bool ok = p < 81; int pc = ok ? p : 80;
    float acc[8];
#pragma unroll
    for (int oo = 0; oo < 8; ++oo) acc[oo] = b2[o0 + oo];
    for (int j = 0; j < 32; ++j) {
      float v = ze_s[j * 81 + pc];
#pragma unroll
      for (int oo = 0; oo < 8; ++oo)
        acc[oo] = fmaf(v, w2[j * 32 + o0 + oo], acc[oo]);
    }
    if (ok) {
#pragma unroll
      for (int oo = 0; oo < 8; ++oo) {
        zb[(o0 + oo) * 81 + p] = acc[oo];
        ztb[p * 32 + o0 + oo] = acc[oo];
      }
    }
  }
}

// ee[k] = ||emb_k||^2
__global__ void k_ee(const float* __restrict__ emb, float* __restrict__ ee) {
  int k = blockIdx.x * 256 + threadIdx.x;
  if (k < 512) {
    const float4* e = (const float4*)(emb + k * 32);
    float s = 0.0f;
#pragma unroll
    for (int q = 0; q < 8; ++q) {
      float4 v = e[q];
      s += v.x * v.x + v.y * v.y + v.z * v.z + v.w * v.w;
    }
    ee[k] = s;
  }
}

// VQ + fused dw1: thread = (pixel, 128-code quarter); after argmin, wave sub
// computes dw1 och group sub*4..+3 from emb[bif] (weights wave-uniform -> s_load).
__global__ void __launch_bounds__(256) k_vq2g(const float* __restrict__ zt,
                                              const float* __restrict__ emb,
                                              const float* __restrict__ ee,
                                              const float* __restrict__ w1,
                                              const float* __restrict__ db1,
                                              const float* __restrict__ g1,
                                              const float* __restrict__ bb1,
                                              const float* __restrict__ bm1,
                                              const float* __restrict__ bv1,
                                              float* __restrict__ lat_out,
                                              float* __restrict__ zqx,
                                              float* __restrict__ G) {
  __shared__ float bd_s[4][64];
  __shared__ int   bi_s[4][64];
  __shared__ int   bif[64];
  int t = threadIdx.x;
  int lane = t & 63, sub = t >> 6;
  int sub_u = __builtin_amdgcn_readfirstlane(sub);
  int pix = blockIdx.x * 64 + lane;                  // 648*64 = 41472 exact
  float z[32];
  {
    const float4* zr = (const float4*)(zt + (size_t)pix * 32);
#pragma unroll
    for (int q = 0; q < 8; ++q) {
      float4 v = zr[q];
      z[q * 4] = v.x; z[q * 4 + 1] = v.y; z[q * 4 + 2] = v.z; z[q * 4 + 3] = v.w;
    }
  }
  const float* ebase = emb + sub_u * 128 * 32;
  const float* eeb   = ee + sub_u * 128;
  int kbase = sub_u * 128;
  float best = FLT_MAX;
  int bi = kbase;
  for (int kk = 0; kk < 128; kk += 2) {
    const float* e0 = ebase + kk * 32;
    const float* e1 = e0 + 32;
    float d0a = 0.f, d0b = 0.f, d1a = 0.f, d1b = 0.f;
#pragma unroll
    for (int c = 0; c < 32; c += 2) {
      d0a = fmaf(z[c], e0[c], d0a);
      d0b = fmaf(z[c + 1], e0[c + 1], d0b);
      d1a = fmaf(z[c], e1[c], d1a);
      d1b = fmaf(z[c + 1], e1[c + 1], d1b);
    }
    float d0 = fmaf(-2.0f, d0a + d0b, eeb[kk]);
    float d1 = fmaf(-2.0f, d1a + d1b, eeb[kk + 1]);
    if (d0 < best) { best = d0; bi = kbase + kk; }
    if (d1 < best) { best = d1; bi = kbase + kk + 1; }
  }
  bd_s[sub][lane] = best;
  bi_s[sub][lane] = bi;
  __syncthreads();
  if (t < 64) {
    float bd = bd_s[0][t]; int b = bi_s[0][t];
#pragma unroll
    for (int q = 1; q < 4; ++q)
      if (bd_s[q][t] < bd) { bd = bd_s[q][t]; b = bi_s[q][t]; }
    lat_out[blockIdx.x * 64 + t] = (float)b;
    bif[t] = b;
  }
  __syncthreads();
  int pix0 = blockIdx.x * 64;
  // zqx write (cooperative, exact coverage)
  for (int idx = t; idx < 2048; idx += 256) {
    int c = idx >> 6, pl = idx & 63;
    int pg = pix0 + pl;
    int nn = pg / 81, pp = pg - nn * 81;
    zqx[nn * 2592 + c * 81 + pp] = emb[bif[pl] * 32 + c];
  }
  // fused dw1: each lane owns its pixel's code row; wave sub -> och sub*4..+3
  {
    int pg = pix0 + lane;
    int nn = pg / 81, pp = pg - nn * 81;
    float e[32];
    const float4* er = (const float4*)(emb + bif[lane] * 32);
#pragma unroll
    for (int q = 0; q < 8; ++q) {
      float4 v = er[q];
      e[q * 4] = v.x; e[q * 4 + 1] = v.y; e[q * 4 + 2] = v.z; e[q * 4 + 3] = v.w;
    }
    float accd[4];
#pragma unroll
    for (int oo = 0; oo < 4; ++oo) accd[oo] = db1[sub_u * 4 + oo];
#pragma unroll
    for (int i = 0; i < 32; ++i) {
      float ev = e[i];
#pragma unroll
      for (int oo = 0; oo < 4; ++oo)
        accd[oo] = fmaf(ev, w1[i * 16 + sub_u * 4 + oo], accd[oo]);
    }
#pragma unroll
    for (int oo = 0; oo < 4; ++oo) {
      int o = sub_u * 4 + oo;
      float s = g1[o] / sqrtf(bv1[o] + BN_EPS);
      float sh = bb1[o] - bm1[o] * s;
      G[nn * 1296 + o * 81 + pp] = fmaxf(accd[oo] * s + sh, 0.0f);
    }
  }
}

// ---------------- decoder ----------------
// dw2 v2: convT 16->16 k4 s2 p1, 9->18. 2x2 output block x 4 chans, scalar weights.
__global__ void __launch_bounds__(256) k_dw2(const float* __restrict__ in,
                      const float* __restrict__ w, const float* __restrict__ bias,
                      const float* __restrict__ g, const float* __restrict__ bb,
                      const float* __restrict__ bm, const float* __restrict__ bv,
                      float* __restrict__ out) {
  int t = threadIdx.x;
  int lane = t & 63;
  int og = __builtin_amdgcn_readfirstlane(t >> 6);   // 0..3 -> o = og*4+oo
  int idx = blockIdx.x * 64 + lane;                  // [0, 41472)
  int n = idx / 81, blk = idx - n * 81;
  int iy = blk / 9, ix = blk - iy * 9;
  const float* ib = in + n * 1296;
  int r0 = iy - 1, r2 = iy + 1, c0 = ix - 1, c2 = ix + 1;
  bool r0ok = r0 >= 0, r2ok = r2 < 9, c0ok = c0 >= 0, c2ok = c2 < 9;
  int r0c = r0ok ? r0 : 0, r2c = r2ok ? r2 : 8;
  int c0c = c0ok ? c0 : 0, c2c = c2ok ? c2 : 8;
  float acc[4][2][2];
#pragma unroll
  for (int oo = 0; oo < 4; ++oo)
#pragma unroll
    for (int dy = 0; dy < 2; ++dy)
#pragma unroll
      for (int dx = 0; dx < 2; ++dx) acc[oo][dy][dx] = 0.0f;
  for (int i = 0; i < 16; ++i) {
    const float* ch = ib + i * 81;
    float v[3][3];
    v[1][1] = ch[iy * 9 + ix];
    v[1][0] = c0ok ? ch[iy * 9 + c0c] : 0.0f;
    v[1][2] = c2ok ? ch[iy * 9 + c2c] : 0.0f;
    v[0][1] = r0ok ? ch[r0c * 9 + ix] : 0.0f;
    v[0][0] = (r0ok & c0ok) ? ch[r0c * 9 + c0c] : 0.0f;
    v[0][2] = (r0ok & c2ok) ? ch[r0c * 9 + c2c] : 0.0f;
    v[2][1] = r2ok ? ch[r2c * 9 + ix] : 0.0f;
    v[2][0] = (r2ok & c0ok) ? ch[r2c * 9 + c0c] : 0.0f;
    v[2][2] = (r2ok & c2ok) ? ch[r2c * 9 + c2c] : 0.0f;
    const float* wb = w + (i * 16 + og * 4) * 16;    // uniform -> scalar loads
#pragma unroll
    for (int oo = 0; oo < 4; ++oo) {
      const float* wo = wb + oo * 16;
      acc[oo][0][0] = fmaf(v[1][1], wo[1 * 4 + 1], acc[oo][0][0]);
      acc[oo][0][0] = fmaf(v[1][0], wo[1 * 4 + 3], acc[oo][0][0]);
      acc[oo][0][0] = fmaf(v[0][1], wo[3 * 4 + 1], acc[oo][0][0]);
      acc[oo][0][0] = fmaf(v[0][0], wo[3 * 4 + 3], acc[oo][0][0]);
      acc[oo][0][1] = fmaf(v[1][1], wo[1 * 4 + 2], acc[oo][0][1]);
      acc[oo][0][1] = fmaf(v[1][2], wo[1 * 4 + 0], acc[oo][0][1]);
      acc[oo][0][1] = fmaf(v[0][1], wo[3 * 4 + 2], acc[oo][0][1]);
      acc[oo][0][1] = fmaf(v[0][2], wo[3 * 4 + 0], acc[oo][0][1]);
      acc[oo][1][0] = fmaf(v[1][1], wo[2 * 4 + 1], acc[oo][1][0]);
      acc[oo][1][0] = fmaf(v[1][0], wo[2 * 4 + 3], acc[oo][1][0]);
      acc[oo][1][0] = fmaf(v[2][1], wo[0 * 4 + 1], acc[oo][1][0]);
      acc[oo][1][0] = fmaf(v[2][0], wo[0 * 4 + 3], acc[oo][1][0]);
      acc[oo][1][1] = fmaf(v[1][1], wo[2 * 4 + 2], acc[oo][1][1]);
      acc[oo][1][1] = fmaf(v[1][2], wo[2 * 4 + 0], acc[oo][1][1]);
      acc[oo][1][1] = fmaf(v[2][1], wo[0 * 4 + 2], acc[oo][1][1]);
      acc[oo][1][1] = fmaf(v[2][2], wo[0 * 4 + 0], acc[oo][1][1]);
    }
  }
  float* ob = out + n * 5184 + (2 * iy) * 18 + 2 * ix;
#pragma unroll
  for (int oo = 0; oo < 4; ++oo) {
    int o = og * 4 + oo;
    float s = g[o] / sqrtf(bv[o] + BN_EPS);
    float sh = bb[o] - bm[o] * s;
    float bo = bias[o];
    float r00 = fmaxf((acc[oo][0][0] + bo) * s + sh, 0.0f);
    float r01 = fmaxf((acc[oo][0][1] + bo) * s + sh, 0.0f);
    float r10 = fmaxf((acc[oo][1][0] + bo) * s + sh, 0.0f);
    float r11 = fmaxf((acc[oo][1][1] + bo) * s + sh, 0.0f);
    float* op = ob + o * 324;
    *(float2*)&op[0]  = make_float2(r00, r01);
    *(float2*)&op[18] = make_float2(r10, r11);
  }
}

// dw3: convT 16->16 k2 s2 p1, 18->34. INPUT-STATIONARY.
__global__ void k_dw3(const float* __restrict__ in, const float* __restrict__ w,
                      const float* __restrict__ bias,
                      const float* __restrict__ g, const float* __restrict__ bb,
                      const float* __restrict__ bm, const float* __restrict__ bv,
                      float* __restrict__ out) {
  int t = blockIdx.x * 256 + threadIdx.x;   // 165888 total
  int ii = t % 324; int n = t / 324;
  int iy = ii / 18, ix = ii % 18;
  const float* ib = in + n * 5184 + iy * 18 + ix;
  float acc[4][16];
#pragma unroll
  for (int a = 0; a < 4; ++a)
#pragma unroll
    for (int o = 0; o < 16; ++o) acc[a][o] = 0.0f;
  for (int i = 0; i < 16; ++i) {
    float v = ib[i * 324];
    const float4* wr = (const float4*)(w + i * 64);
#pragma unroll
    for (int o = 0; o < 16; ++o) {
      float4 wt = wr[o];
      acc[0][o] = fmaf(v, wt.x, acc[0][o]);
      acc[1][o] = fmaf(v, wt.y, acc[1][o]);
      acc[2][o] = fmaf(v, wt.z, acc[2][o]);
      acc[3][o] = fmaf(v, wt.w, acc[3][o]);
    }
  }
  int yo0 = 2 * iy - 1, xo0 = 2 * ix - 1;
  float* ob = out + n * 18496;
#pragma unroll
  for (int o = 0; o < 16; ++o) {
    float s = g[o] / sqrtf(bv[o] + BN_EPS);
    float sh = bb[o] - bm[o] * s;
    float bo = bias[o];
#pragma unroll
    for (int a = 0; a < 2; ++a)
#pragma unroll
      for (int b = 0; b < 2; ++b) {
        int yo = yo0 + a, xo = xo0 + b;
        if (yo >= 0 && yo < 34 && xo >= 0 && xo < 34)
          ob[o * 1156 + yo * 34 + xo] = fmaxf((acc[a * 2 + b][o] + bo) * s + sh, 0.0f);
      }
  }
}

// dw4 (k2 s2 p0, 34->68) + bn + relu + ow + ob, INPUT-STATIONARY fused.
__global__ void k_dw4ow(const float* __restrict__ in, const float* __restrict__ w,
                        const float* __restrict__ bias,
                        const float* __restrict__ g, const float* __restrict__ bb,
                        const float* __restrict__ bm, const float* __restrict__ bv,
                        const float* __restrict__ oww, const float* __restrict__ obb,
                        float* __restrict__ out) {
  int t = blockIdx.x * 256 + threadIdx.x;   // 591872 total
  int ii = t % 1156; int n = t / 1156;
  int iy = ii / 34, ix = ii % 34;
  const float* ib = in + n * 18496 + iy * 34 + ix;
  float acc[4][16];
#pragma unroll
  for (int a = 0; a < 4; ++a)
#pragma unroll
    for (int o = 0; o < 16; ++o) acc[a][o] = 0.0f;
  for (int i = 0; i < 16; ++i) {
    float v = ib[i * 1156];
    const float4* wr = (const float4*)(w + i * 64);
#pragma unroll
    for (int o = 0; o < 16; ++o) {
      float4 wt = wr[o];
      acc[0][o] = fmaf(v, wt.x, acc[0][o]);
      acc[1][o] = fmaf(v, wt.y, acc[1][o]);
      acc[2][o] = fmaf(v, wt.z, acc[2][o]);
      acc[3][o] = fmaf(v, wt.w, acc[3][o]);
    }
  }
  float r[4];
#pragma unroll
  for (int a = 0; a < 4; ++a) r[a] = obb[0];
#pragma unroll
  for (int o = 0; o < 16; ++o) {
    float s = g[o] / sqrtf(bv[o] + BN_EPS);
    float sh = bb[o] - bm[o] * s;
    float bo = bias[o];
    float wo = oww[o];
#pragma unroll
    for (int a = 0; a < 4; ++a)
      r[a] += fmaxf((acc[a][o] + bo) * s + sh, 0.0f) * wo;
  }
  float* ob = out + n * 4624 + 2 * ix;
  *(float2*)&ob[(2 * iy) * 68]     = make_float2(r[0], r[1]);
  *(float2*)&ob[(2 * iy + 1) * 68] = make_float2(r[2], r[3]);
}

extern "C" void kernel_launch(void* const* d_in, const int* in_sizes, int n_in,
                              void* d_out, int out_size, void* d_ws, size_t ws_size,
                              hipStream_t stream) {
  const float* x     = (const float*)d_in[0];
  const float* ew1   = (const float*)d_in[1];
  const float* eb1   = (const float*)d_in[2];
  const float* ew2   = (const float*)d_in[3];
  const float* eb2   = (const float*)d_in[4];
  const float* ew3   = (const float*)d_in[5];
  const float* eb3   = (const float*)d_in[6];
  const float* ew4   = (const float*)d_in[7];
  const float* eb4   = (const float*)d_in[8];
  const float* fc21w = (const float*)d_in[9];
  const float* fc21b = (const float*)d_in[10];
  const float* fc22w = (const float*)d_in[11];
  const float* fc22b = (const float*)d_in[12];
  const float* fc3w  = (const float*)d_in[13];
  const float* fc3b  = (const float*)d_in[14];
  const float* cw1   = (const float*)d_in[15];
  const float* cb1   = (const float*)d_in[16];
  const float* cw2   = (const float*)d_in[17];
  const float* cb2   = (const float*)d_in[18];
  const float* dw1   = (const float*)d_in[19];
  const float* db1   = (const float*)d_in[20];
  const float* dw2   = (const float*)d_in[21];
  const float* db2   = (const float*)d_in[22];
  const float* dw3   = (const float*)d_in[23];
  const float* db3   = (const float*)d_in[24];
  const float* dw4   = (const float*)d_in[25];
  const float* db4   = (const float*)d_in[26];
  const float* oww   = (const float*)d_in[27];
  const float* obb   = (const float*)d_in[28];
  const float* bn1g  = (const float*)d_in[29];
  const float* bn1b  = (const float*)d_in[30];
  const float* bn1m  = (const float*)d_in[31];
  const float* bn1v  = (const float*)d_in[32];
  const float* bn2g  = (const float*)d_in[33];
  const float* bn2b  = (const float*)d_in[34];
  const float* bn2m  = (const float*)d_in[35];
  const float* bn2v  = (const float*)d_in[36];
  const float* bn3g  = (const float*)d_in[37];
  const float* bn3b  = (const float*)d_in[38];
  const float* bn3m  = (const float*)d_in[39];
  const float* bn3v  = (const float*)d_in[40];
  const float* bn4g  = (const float*)d_in[41];
  const float* bn4b  = (const float*)d_in[42];
  const float* bn4m  = (const float*)d_in[43];
  const float* bn4v  = (const float*)d_in[44];
  const float* cbn1g = (const float*)d_in[45];
  const float* cbn1b = (const float*)d_in[46];
  const float* cbn1m = (const float*)d_in[47];
  const float* cbn1v = (const float*)d_in[48];
  const float* dbn1g = (const float*)d_in[49];
  const float* dbn1b = (const float*)d_in[50];
  const float* dbn1m = (const float*)d_in[51];
  const float* dbn1v = (const float*)d_in[52];
  const float* dbn2g = (const float*)d_in[53];
  const float* dbn2b = (const float*)d_in[54];
  const float* dbn2m = (const float*)d_in[55];
  const float* dbn2v = (const float*)d_in[56];
  const float* dbn3g = (const float*)d_in[57];
  const float* dbn3b = (const float*)d_in[58];
  const float* dbn3m = (const float*)d_in[59];
  const float* dbn3v = (const float*)d_in[60];
  const float* dbn4g = (const float*)d_in[61];
  const float* dbn4b = (const float*)d_in[62];
  const float* dbn4m = (const float*)d_in[63];
  const float* dbn4v = (const float*)d_in[64];
  const float* emb   = (const float*)d_in[65];

  float* out = (float*)d_out;
  float* xt_o  = out;                 // [512,1,68,68]  2,367,488
  float* z_o   = out + 2367488;       // [512,64]
  float* mu_o  = out + 2400256;       // [512,64]
  float* lv_o  = out + 2433024;       // [512,64]
  float* zex_o = out + 2465792;       // [512,32,9,9]  1,327,104
  float* zqx_o = out + 3792896;       // [512,32,9,9]
  float* lat_o = out + 5120000;       // [512,9,9]

  float* ws = (float*)d_ws;
  // lifetime-based reuse; high-water ~13.67M floats (54.7 MB)
  float* A    = ws;                   // padded NCHW [512,16,34,34] = 9,469,952; conv1->conv2
  float* Bt   = ws + 9469952;         // [512,16,16,16] 2,097,152; conv2->c34
  float* Dhl  = ws;                   // hl [512,10368] 5,308,416; c34->gemm1 (A dead)
  float* part = ws + 9469952;         // 4,194,304; gemm1->fc_red (Bt dead)
  float* Eco  = ws;                   // [512,10368]; fc3->k_cw (Dhl dead)
  float* zt   = ws + 9469952;         // [41472,32] 1,327,104; k_cw->vq2g (part dead)
  float* G    = ws + 10797056;        // [512,16,9,9] 663,552; vq2g->dw2
  float* H    = ws + 11460608;        // [512,16,18,18] 2,654,208; dw2->dw3
  float* I    = ws;                   // [512,16,34,34] 9,469,952; dw3->dw4 (Eco dead)
  float* eev  = ws + 14114816;        // [512]
  float* wr2  = ws + 14115328;        // [4096] reordered conv2 weights

  k_pad0<<<512, 256, 0, stream>>>(A);
  k_wr2<<<16, 256, 0, stream>>>(ew2, wr2);
  k_conv1<<<512, 256, 0, stream>>>(x, ew1, eb1, bn1g, bn1b, bn1m, bn1v, A);
  k_conv2<<<2048, 256, 0, stream>>>(A, wr2, eb2, bn2g, bn2b, bn2m, bn2v, Bt);
  k_c34<<<1024, 256, 0, stream>>>(Bt, ew3, eb3, bn3g, bn3b, bn3m, bn3v,
                                  ew4, eb4, bn4g, bn4b, bn4m, bn4v, Dhl);
  k_gemm1<<<dim3(64, 8), 256, 0, stream>>>(Dhl, fc21w, fc22w, part);
  k_fc_red<<<256, 256, 0, stream>>>(part, fc21b, fc22b, z_o, mu_o, lv_o);
  k_ee<<<2, 256, 0, stream>>>(emb, eev);
  k_fc3<<<dim3(81, 16), 128, 0, stream>>>(z_o, fc3w, fc3b, Eco);
  k_cw<<<512, 256, 0, stream>>>(Eco, cw1, cb1, cbn1g, cbn1b, cbn1m, cbn1v, cw2, cb2, zex_o, zt);
  k_vq2g<<<648, 256, 0, stream>>>(zt, emb, eev, dw1, db1, dbn1g, dbn1b, dbn1m, dbn1v,
                                  lat_o, zqx_o, G);
  k_dw2<<<648, 256, 0, stream>>>(G, dw2, db2, dbn2g, dbn2b, dbn2m, dbn2v, H);
  k_dw3<<<648, 256, 0, stream>>>(H, dw3, db3, dbn3g, dbn3b, dbn3m, dbn3v, I);
  k_dw4ow<<<2312, 256, 0, stream>>>(I, dw4, db4, dbn4g, dbn4b, dbn4m, dbn4v, oww, obb, xt_o);
}

// Round 15
// 455.225 us; speedup vs baseline: 1.0612x; 1.0612x over previous
//
#include <hip/hip_runtime.h>
#include <math.h>
#include <float.h>

#define BN_EPS 1e-5f

__device__ __forceinline__ float bn_apply(float y, float g, float b, float m, float v) {
  float s = g / sqrtf(v + BN_EPS);
  return y * s + (b - m * s);
}

// zero the border pixels of padded NCHW A [512][16][34][34]
__global__ void k_pad0(float* __restrict__ A) {
  int n = blockIdx.x, t = threadIdx.x;
  float* ab = A + n * 18496;
  for (int idx = t; idx < 2112; idx += 256) {   // 16 ch * 132 border px
    int ch = idx / 132, b = idx - ch * 132;
    int r, c;
    if (b < 34)       { r = 0;      c = b; }
    else if (b < 68)  { r = 33;     c = b - 34; }
    else if (b < 100) { r = b - 67; c = 0; }    // rows 1..32
    else              { r = b - 99; c = 33; }
    ab[ch * 1156 + r * 34 + c] = 0.0f;
  }
}

// reorder conv2 weights: wr2[og*1024 + i*64 + k*4 + oo] = w[(og*4+oo)*256 + i*16 + k]
__global__ void k_wr2(const float* __restrict__ w, float* __restrict__ wr2) {
  int idx = blockIdx.x * 256 + threadIdx.x;   // 4096
  int og = idx >> 10, rem = idx & 1023;
  int i = rem >> 6, r2 = rem & 63;
  int k = r2 >> 2, oo = r2 & 3;
  wr2[idx] = w[(og * 4 + oo) * 256 + i * 16 + k];
}

// ---------------- encoder ----------------
// conv1 (reverted to proven R12 form): [512,1,64,64] -> padded NCHW A interior,
// k4 s2 p1 + bn + relu. One thread per (n,y,x), 16 out ch. ~48 VGPR, 8 waves/SIMD.
__global__ void k_conv1(const float* __restrict__ x, const float* __restrict__ w,
                        const float* __restrict__ bias,
                        const float* __restrict__ g, const float* __restrict__ bb,
                        const float* __restrict__ bm, const float* __restrict__ bv,
                        float* __restrict__ A) {
  int t = blockIdx.x * 256 + threadIdx.x;   // 524288 total
  int xo = t & 31, yo = (t >> 5) & 31, n = t >> 10;
  int iy0 = 2 * yo - 1, ix0 = 2 * xo - 1;
  const float* xb = x + n * 4096;
  float p[16];
#pragma unroll
  for (int ky = 0; ky < 4; ++ky)
#pragma unroll
    for (int kx = 0; kx < 4; ++kx) {
      int iy = iy0 + ky, ix = ix0 + kx;
      bool ok = (iy >= 0) & (iy < 64) & (ix >= 0) & (ix < 64);
      p[ky * 4 + kx] = ok ? xb[iy * 64 + ix] : 0.0f;
    }
  float* ob = A + n * 18496 + (yo + 1) * 34 + (xo + 1);
#pragma unroll
  for (int o = 0; o < 16; ++o) {
    float acc = bias[o];
#pragma unroll
    for (int k = 0; k < 16; ++k) acc += p[k] * w[o * 16 + k];
    acc = bn_apply(acc, g[o], bb[o], bm[o], bv[o]);
    ob[o * 1156] = fmaxf(acc, 0.0f);
  }
}

// conv2 v8 (proven R13): padded NCHW in, thread=(pixel, og of 4 och).
__global__ void __launch_bounds__(256) k_conv2(const float* __restrict__ A,
                        const float* __restrict__ wr2, const float* __restrict__ bias,
                        const float* __restrict__ g, const float* __restrict__ bb,
                        const float* __restrict__ bm, const float* __restrict__ bv,
                        float* __restrict__ out) {
  int t = threadIdx.x;
  int lane = t & 63;
  int og = __builtin_amdgcn_readfirstlane(t >> 6);   // 0..3
  int idx = blockIdx.x * 64 + lane;                  // [0, 131072) = n*256 + p
  int n = idx >> 8, p = idx & 255;
  int yo = p >> 4, xo = p & 15;
  const float* Ab = A + n * 18496 + (2 * yo) * 34 + 2 * xo;
  const float* wb = wr2 + og * 1024;
  float acc[4];
#pragma unroll
  for (int oo = 0; oo < 4; ++oo) acc[oo] = bias[og * 4 + oo];
  for (int i = 0; i < 16; ++i) {
    const float* ch = Ab + i * 1156;
    float pv[16];
#pragma unroll
    for (int ky = 0; ky < 4; ++ky) {
      float2 a = *(const float2*)(ch + ky * 34);
      float2 b = *(const float2*)(ch + ky * 34 + 2);
      pv[ky * 4 + 0] = a.x; pv[ky * 4 + 1] = a.y;
      pv[ky * 4 + 2] = b.x; pv[ky * 4 + 3] = b.y;
    }
    const float* wt = wb + i * 64;   // [k][oo] contiguous, wave-uniform -> s_load
#pragma unroll
    for (int k = 0; k < 16; ++k) {
#pragma unroll
      for (int oo = 0; oo < 4; ++oo)
        acc[oo] = fmaf(pv[k], wt[k * 4 + oo], acc[oo]);
    }
  }
  float* ob = out + n * 4096 + p;
#pragma unroll
  for (int oo = 0; oo < 4; ++oo) {
    int o = og * 4 + oo;
    float s = g[o] / sqrtf(bv[o] + BN_EPS);
    float sh = bb[o] - bm[o] * s;
    ob[o * 256] = fmaxf(acc[oo] * s + sh, 0.0f);
  }
}

// conv3 + conv4 FUSED. Grid 1024 = (n, half).
__global__ void __launch_bounds__(256) k_c34(const float* __restrict__ in,
    const float* __restrict__ w3, const float* __restrict__ b3,
    const float* __restrict__ g3, const float* __restrict__ bb3,
    const float* __restrict__ bm3, const float* __restrict__ bv3,
    const float* __restrict__ w4, const float* __restrict__ b4,
    const float* __restrict__ g4, const float* __restrict__ bb4,
    const float* __restrict__ bm4, const float* __restrict__ bv4,
    float* __restrict__ hl) {
  __shared__ float xin[4096];
  __shared__ float w3s[1024];
  __shared__ float c3s[16 * 81];
  __shared__ float k3a[16], k3b[16];
  __shared__ float k4a[128], k4b[128];
  int bx = blockIdx.x;
  int n = bx >> 1, half = bx & 1;
  int t = threadIdx.x;
  {
    const float4* iv = (const float4*)(in + n * 4096);
    float4* xv = (float4*)xin;
#pragma unroll
    for (int q = 0; q < 4; ++q) xv[t + 256 * q] = iv[t + 256 * q];
    for (int i = t; i < 1024; i += 256) w3s[i] = w3[i];
  }
  if (t < 16) {
    float s = g3[t] / sqrtf(bv3[t] + BN_EPS);
    k3a[t] = s;
    k3b[t] = b3[t] * s + (bb3[t] - bm3[t] * s);
  } else if (t >= 64 && t < 192) {
    int o = t - 64;
    float s = g4[o] / sqrtf(bv4[o] + BN_EPS);
    k4a[o] = s;
    k4b[o] = b4[o] * s + (bb4[o] - bm4[o] * s);
  }
  __syncthreads();
  for (int idx = t; idx < 1296; idx += 256) {
    int o = idx / 81, p = idx - o * 81;
    int yo = p / 9, xo = p - yo * 9;
    int iy0 = 2 * yo - 1, ix0 = 2 * xo - 1;
    bool ytop = iy0 >= 0, ybot = iy0 + 1 < 16;
    bool xlft = ix0 >= 0, xrgt = ix0 + 1 < 16;
    int iyt = ytop ? iy0 : 0, iyb = ybot ? iy0 + 1 : 15;
    int ixl = xlft ? ix0 : 0, ixr = xrgt ? ix0 + 1 : 15;
    float acc = 0.0f;
#pragma unroll
    for (int i = 0; i < 16; ++i) {
      const float* ch = xin + i * 256;
      float p0 = (ytop & xlft) ? ch[iyt * 16 + ixl] : 0.0f;
      float p1 = (ytop & xrgt) ? ch[iyt * 16 + ixr] : 0.0f;
      float p2 = (ybot & xlft) ? ch[iyb * 16 + ixl] : 0.0f;
      float p3 = (ybot & xrgt) ? ch[iyb * 16 + ixr] : 0.0f;
      float4 wv = *(const float4*)&w3s[(o * 16 + i) * 4];
      acc += p0 * wv.x + p1 * wv.y + p2 * wv.z + p3 * wv.w;
    }
    c3s[idx] = fmaxf(acc * k3a[o] + k3b[o], 0.0f);
  }
  __syncthreads();
  int lane = t & 63;
  int og = __builtin_amdgcn_readfirstlane(t >> 6);   // 0..3
  int o0 = half * 64 + og * 16;
  float* ob = hl + n * 10368;
#pragma unroll
  for (int pass = 0; pass < 2; ++pass) {
    int p = pass * 64 + lane;
    bool ok = p < 81; int pc = ok ? p : 80;
    float acc[16];
#pragma unroll
    for (int oo = 0; oo < 16; ++oo) acc[oo] = 0.0f;
#pragma unroll
    for (int i = 0; i < 16; ++i) {
      float v = c3s[i * 81 + pc];
#pragma unroll
      for (int oo = 0; oo < 16; ++oo)
        acc[oo] = fmaf(v, w4[(o0 + oo) * 16 + i], acc[oo]);
    }
    if (ok) {
#pragma unroll
      for (int oo = 0; oo < 16; ++oo) {
        int o = o0 + oo;
        ob[o * 81 + p] = fmaxf(acc[oo] * k4a[o] + k4b[o], 0.0f);
      }
    }
  }
}

// fc21+fc22 fused split-K GEMM v4 (register double-buffer prefetch).
__global__ void __launch_bounds__(256) k_gemm1(const float* __restrict__ hl,
                                               const float* __restrict__ w21,
                                               const float* __restrict__ w22,
                                               float* __restrict__ part) {
  __shared__ __align__(16) float hs[27 * 68];
  __shared__ __align__(16) float wsh[27 * 128];
  int kc = blockIdx.x, nt = blockIdx.y, t = threadIdx.x;
  int n0 = nt * 64, k0 = kc * 162;
  int jg = t & 31, ng = t >> 5;
  float acc[8][4];
#pragma unroll
  for (int i = 0; i < 8; ++i)
#pragma unroll
    for (int q = 0; q < 4; ++q) acc[i][q] = 0.0f;
  float ph[7], pw[14];
  {
    int ks = k0;
#pragma unroll
    for (int q = 0; q < 7; ++q) {
      int idx = t + q * 256;
      if (idx < 1728) { int nr = idx / 27, kk = idx - nr * 27;
        ph[q] = hl[(n0 + nr) * 10368 + ks + kk]; }
    }
#pragma unroll
    for (int q = 0; q < 14; ++q) {
      int idx = t + q * 256;
      if (idx < 3456) { int r = idx >> 7, c = idx & 127;
        pw[q] = (c < 64) ? w21[(ks + r) * 64 + c] : w22[(ks + r) * 64 + (c - 64)]; }
    }
  }
  for (int s = 0; s < 6; ++s) {
    __syncthreads();
#pragma unroll
    for (int q = 0; q < 7; ++q) {
      int idx = t + q * 256;
      if (idx < 1728) { int nr = idx / 27, kk = idx - nr * 27; hs[kk * 68 + nr] = ph[q]; }
    }
#pragma unroll
    for (int q = 0; q < 14; ++q) {
      int idx = t + q * 256;
      if (idx < 3456) wsh[idx] = pw[q];
    }
    __syncthreads();
    if (s < 5) {
      int ks = k0 + (s + 1) * 27;
#pragma unroll
      for (int q = 0; q < 7; ++q) {
        int idx = t + q * 256;
        if (idx < 1728) { int nr = idx / 27, kk = idx - nr * 27;
          ph[q] = hl[(n0 + nr) * 10368 + ks + kk]; }
      }
#pragma unroll
      for (int q = 0; q < 14; ++q) {
        int idx = t + q * 256;
        if (idx < 3456) { int r = idx >> 7, c = idx & 127;
          pw[q] = (c < 64) ? w21[(ks + r) * 64 + c] : w22[(ks + r) * 64 + (c - 64)]; }
      }
    }
#pragma unroll 9
    for (int kk = 0; kk < 27; ++kk) {
      float4 h0 = *(const float4*)&hs[kk * 68 + ng * 8];
      float4 h1 = *(const float4*)&hs[kk * 68 + ng * 8 + 4];
      float4 wv = *(const float4*)&wsh[kk * 128 + jg * 4];
      float hv[8] = {h0.x, h0.y, h0.z, h0.w, h1.x, h1.y, h1.z, h1.w};
#pragma unroll
      for (int i = 0; i < 8; ++i) {
        acc[i][0] = fmaf(hv[i], wv.x, acc[i][0]);
        acc[i][1] = fmaf(hv[i], wv.y, acc[i][1]);
        acc[i][2] = fmaf(hv[i], wv.z, acc[i][2]);
        acc[i][3] = fmaf(hv[i], wv.w, acc[i][3]);
      }
    }
  }
#pragma unroll
  for (int i = 0; i < 8; ++i) {
    int n = n0 + ng * 8 + i;
    *(float4*)&part[(size_t)(kc * 512 + n) * 128 + jg * 4] =
        make_float4(acc[i][0], acc[i][1], acc[i][2], acc[i][3]);
  }
}

// reduce partials + bias -> z, mu, logvar
__global__ void k_fc_red(const float* __restrict__ part, const float* __restrict__ b21,
                         const float* __restrict__ b22, float* __restrict__ z,
                         float* __restrict__ mu, float* __restrict__ lv) {
  int t = blockIdx.x * 256 + threadIdx.x;   // 65536
  int j = t & 127, n = t >> 7;
  float s = 0.0f;
  for (int kc = 0; kc < 64; ++kc) s += part[(size_t)(kc * 512 + n) * 128 + j];
  if (j < 64) { float r = s + b21[j]; z[n * 64 + j] = r; mu[n * 64 + j] = r; }
  else        { lv[n * 64 + (j - 64)] = s + b22[j - 64]; }
}

// fc3 + relu: [512,64] @ [64,10368]. grid (81, 16 n-tiles), block 128 (m).
__global__ void k_fc3(const float* __restrict__ z, const float* __restrict__ w,
                      const float* __restrict__ b, float* __restrict__ E) {
  int m = blockIdx.x * 128 + threadIdx.x;
  int n0 = blockIdx.y * 32;
  float acc[32];
#pragma unroll
  for (int nn = 0; nn < 32; ++nn) acc[nn] = 0.0f;
  for (int j = 0; j < 64; ++j) {
    float wv = w[j * 10368 + m];
    const float* zb = z + n0 * 64 + j;
#pragma unroll
    for (int nn = 0; nn < 32; ++nn) acc[nn] += zb[nn * 64] * wv;
  }
  float bvv = b[m];
  float* Eb = E + n0 * 10368 + m;
#pragma unroll
  for (int nn = 0; nn < 32; ++nn) Eb[nn * 10368] = fmaxf(acc[nn] + bvv, 0.0f);
}

// fused cw1(128->32)+bn+relu + cw2(32->32). Block per image, wave-uniform o-group.
__global__ void __launch_bounds__(256) k_cw(const float* __restrict__ E,
                     const float* __restrict__ w1, const float* __restrict__ b1,
                     const float* __restrict__ g, const float* __restrict__ bb,
                     const float* __restrict__ bm, const float* __restrict__ bv,
                     const float* __restrict__ w2, const float* __restrict__ b2,
                     float* __restrict__ zex, float* __restrict__ zt) {
  __shared__ float ze_s[2592];
  int n = blockIdx.x, t = threadIdx.x;
  int lane = t & 63;
  int o0 = __builtin_amdgcn_readfirstlane(t >> 6) * 8;   // 0,8,16,24
  const float* co = E + n * 10368;
#pragma unroll
  for (int pass = 0; pass < 2; ++pass) {
    int p = pass * 64 + lane;
    bool ok = p < 81; int pc = ok ? p : 80;
    float acc[8];
#pragma unroll
    for (int oo = 0; oo < 8; ++oo) acc[oo] = b1[o0 + oo];
    for (int i = 0; i < 128; ++i) {
      float v = co[i * 81 + pc];
#pragma unroll
      for (int oo = 0; oo < 8; ++oo)
        acc[oo] = fmaf(v, w1[i * 32 + o0 + oo], acc[oo]);
    }
#pragma unroll
    for (int oo = 0; oo < 8; ++oo) {
      int o = o0 + oo;
      float r = bn_apply(acc[oo], g[o], bb[o], bm[o], bv[o]);
      if (ok) ze_s[o * 81 + p] = fmaxf(r, 0.0f);
    }
  }
  __syncthreads();
  float* zb = zex + n * 2592;
  float* ztb = zt + n * 81 * 32;
#pragma unroll
  for (int pass = 0; pass < 2; ++pass) {
    int p = pass * 64 + lane;
    bool ok = p < 81; int pc = ok ? p : 80;
    float acc[8];
#pragma unroll
    for (int oo = 0; oo < 8; ++oo) acc[oo] = b2[o0 + oo];
    for (int j = 0; j < 32; ++j) {
      float v = ze_s[j * 81 + pc];
#pragma unroll
      for (int oo = 0; oo < 8; ++oo)
        acc[oo] = fmaf(v, w2[j * 32 + o0 + oo], acc[oo]);
    }
    if (ok) {
#pragma unroll
      for (int oo = 0; oo < 8; ++oo) {
        zb[(o0 + oo) * 81 + p] = acc[oo];
        ztb[p * 32 + o0 + oo] = acc[oo];
      }
    }
  }
}

// ee[k] = ||emb_k||^2
__global__ void k_ee(const float* __restrict__ emb, float* __restrict__ ee) {
  int k = blockIdx.x * 256 + threadIdx.x;
  if (k < 512) {
    const float4* e = (const float4*)(emb + k * 32);
    float s = 0.0f;
#pragma unroll
    for (int q = 0; q < 8; ++q) {
      float4 v = e[q];
      s += v.x * v.x + v.y * v.y + v.z * v.z + v.w * v.w;
    }
    ee[k] = s;
  }
}

// VQ + fused dw1 (proven R14): thread = (pixel, 128-code quarter); after argmin,
// wave sub computes dw1 och group sub*4..+3 from emb[bif].
__global__ void __launch_bounds__(256) k_vq2g(const float* __restrict__ zt,
                                              const float* __restrict__ emb,
                                              const float* __restrict__ ee,
                                              const float* __restrict__ w1,
                                              const float* __restrict__ db1,
                                              const float* __restrict__ g1,
                                              const float* __restrict__ bb1,
                                              const float* __restrict__ bm1,
                                              const float* __restrict__ bv1,
                                              float* __restrict__ lat_out,
                                              float* __restrict__ zqx,
                                              float* __restrict__ G) {
  __shared__ float bd_s[4][64];
  __shared__ int   bi_s[4][64];
  __shared__ int   bif[64];
  int t = threadIdx.x;
  int lane = t & 63, sub = t >> 6;
  int sub_u = __builtin_amdgcn_readfirstlane(sub);
  int pix = blockIdx.x * 64 + lane;                  // 648*64 = 41472 exact
  float z[32];
  {
    const float4* zr = (const float4*)(zt + (size_t)pix * 32);
#pragma unroll
    for (int q = 0; q < 8; ++q) {
      float4 v = zr[q];
      z[q * 4] = v.x; z[q * 4 + 1] = v.y; z[q * 4 + 2] = v.z; z[q * 4 + 3] = v.w;
    }
  }
  const float* ebase = emb + sub_u * 128 * 32;
  const float* eeb   = ee + sub_u * 128;
  int kbase = sub_u * 128;
  float best = FLT_MAX;
  int bi = kbase;
  for (int kk = 0; kk < 128; kk += 2) {
    const float* e0 = ebase + kk * 32;
    const float* e1 = e0 + 32;
    float d0a = 0.f, d0b = 0.f, d1a = 0.f, d1b = 0.f;
#pragma unroll
    for (int c = 0; c < 32; c += 2) {
      d0a = fmaf(z[c], e0[c], d0a);
      d0b = fmaf(z[c + 1], e0[c + 1], d0b);
      d1a = fmaf(z[c], e1[c], d1a);
      d1b = fmaf(z[c + 1], e1[c + 1], d1b);
    }
    float d0 = fmaf(-2.0f, d0a + d0b, eeb[kk]);
    float d1 = fmaf(-2.0f, d1a + d1b, eeb[kk + 1]);
    if (d0 < best) { best = d0; bi = kbase + kk; }
    if (d1 < best) { best = d1; bi = kbase + kk + 1; }
  }
  bd_s[sub][lane] = best;
  bi_s[sub][lane] = bi;
  __syncthreads();
  if (t < 64) {
    float bd = bd_s[0][t]; int b = bi_s[0][t];
#pragma unroll
    for (int q = 1; q < 4; ++q)
      if (bd_s[q][t] < bd) { bd = bd_s[q][t]; b = bi_s[q][t]; }
    lat_out[blockIdx.x * 64 + t] = (float)b;
    bif[t] = b;
  }
  __syncthreads();
  int pix0 = blockIdx.x * 64;
  for (int idx = t; idx < 2048; idx += 256) {
    int c = idx >> 6, pl = idx & 63;
    int pg = pix0 + pl;
    int nn = pg / 81, pp = pg - nn * 81;
    zqx[nn * 2592 + c * 81 + pp] = emb[bif[pl] * 32 + c];
  }
  {
    int pg = pix0 + lane;
    int nn = pg / 81, pp = pg - nn * 81;
    float e[32];
    const float4* er = (const float4*)(emb + bif[lane] * 32);
#pragma unroll
    for (int q = 0; q < 8; ++q) {
      float4 v = er[q];
      e[q * 4] = v.x; e[q * 4 + 1] = v.y; e[q * 4 + 2] = v.z; e[q * 4 + 3] = v.w;
    }
    float accd[4];
#pragma unroll
    for (int oo = 0; oo < 4; ++oo) accd[oo] = db1[sub_u * 4 + oo];
#pragma unroll
    for (int i = 0; i < 32; ++i) {
      float ev = e[i];
#pragma unroll
      for (int oo = 0; oo < 4; ++oo)
        accd[oo] = fmaf(ev, w1[i * 16 + sub_u * 4 + oo], accd[oo]);
    }
#pragma unroll
    for (int oo = 0; oo < 4; ++oo) {
      int o = sub_u * 4 + oo;
      float s = g1[o] / sqrtf(bv1[o] + BN_EPS);
      float sh = bb1[o] - bm1[o] * s;
      G[nn * 1296 + o * 81 + pp] = fmaxf(accd[oo] * s + sh, 0.0f);
    }
  }
}

// ---------------- decoder ----------------
// dw2 v2: convT 16->16 k4 s2 p1, 9->18. 2x2 output block x 4 chans, scalar weights.
__global__ void __launch_bounds__(256) k_dw2(const float* __restrict__ in,
                      const float* __restrict__ w, const float* __restrict__ bias,
                      const float* __restrict__ g, const float* __restrict__ bb,
                      const float* __restrict__ bm, const float* __restrict__ bv,
                      float* __restrict__ out) {
  int t = threadIdx.x;
  int lane = t & 63;
  int og = __builtin_amdgcn_readfirstlane(t >> 6);   // 0..3 -> o = og*4+oo
  int idx = blockIdx.x * 64 + lane;                  // [0, 41472)
  int n = idx / 81, blk = idx - n * 81;
  int iy = blk / 9, ix = blk - iy * 9;
  const float* ib = in + n * 1296;
  int r0 = iy - 1, r2 = iy + 1, c0 = ix - 1, c2 = ix + 1;
  bool r0ok = r0 >= 0, r2ok = r2 < 9, c0ok = c0 >= 0, c2ok = c2 < 9;
  int r0c = r0ok ? r0 : 0, r2c = r2ok ? r2 : 8;
  int c0c = c0ok ? c0 : 0, c2c = c2ok ? c2 : 8;
  float acc[4][2][2];
#pragma unroll
  for (int oo = 0; oo < 4; ++oo)
#pragma unroll
    for (int dy = 0; dy < 2; ++dy)
#pragma unroll
      for (int dx = 0; dx < 2; ++dx) acc[oo][dy][dx] = 0.0f;
  for (int i = 0; i < 16; ++i) {
    const float* ch = ib + i * 81;
    float v[3][3];
    v[1][1] = ch[iy * 9 + ix];
    v[1][0] = c0ok ? ch[iy * 9 + c0c] : 0.0f;
    v[1][2] = c2ok ? ch[iy * 9 + c2c] : 0.0f;
    v[0][1] = r0ok ? ch[r0c * 9 + ix] : 0.0f;
    v[0][0] = (r0ok & c0ok) ? ch[r0c * 9 + c0c] : 0.0f;
    v[0][2] = (r0ok & c2ok) ? ch[r0c * 9 + c2c] : 0.0f;
    v[2][1] = r2ok ? ch[r2c * 9 + ix] : 0.0f;
    v[2][0] = (r2ok & c0ok) ? ch[r2c * 9 + c0c] : 0.0f;
    v[2][2] = (r2ok & c2ok) ? ch[r2c * 9 + c2c] : 0.0f;
    const float* wb = w + (i * 16 + og * 4) * 16;    // uniform -> scalar loads
#pragma unroll
    for (int oo = 0; oo < 4; ++oo) {
      const float* wo = wb + oo * 16;
      acc[oo][0][0] = fmaf(v[1][1], wo[1 * 4 + 1], acc[oo][0][0]);
      acc[oo][0][0] = fmaf(v[1][0], wo[1 * 4 + 3], acc[oo][0][0]);
      acc[oo][0][0] = fmaf(v[0][1], wo[3 * 4 + 1], acc[oo][0][0]);
      acc[oo][0][0] = fmaf(v[0][0], wo[3 * 4 + 3], acc[oo][0][0]);
      acc[oo][0][1] = fmaf(v[1][1], wo[1 * 4 + 2], acc[oo][0][1]);
      acc[oo][0][1] = fmaf(v[1][2], wo[1 * 4 + 0], acc[oo][0][1]);
      acc[oo][0][1] = fmaf(v[0][1], wo[3 * 4 + 2], acc[oo][0][1]);
      acc[oo][0][1] = fmaf(v[0][2], wo[3 * 4 + 0], acc[oo][0][1]);
      acc[oo][1][0] = fmaf(v[1][1], wo[2 * 4 + 1], acc[oo][1][0]);
      acc[oo][1][0] = fmaf(v[1][0], wo[2 * 4 + 3], acc[oo][1][0]);
      acc[oo][1][0] = fmaf(v[2][1], wo[0 * 4 + 1], acc[oo][1][0]);
      acc[oo][1][0] = fmaf(v[2][0], wo[0 * 4 + 3], acc[oo][1][0]);
      acc[oo][1][1] = fmaf(v[1][1], wo[2 * 4 + 2], acc[oo][1][1]);
      acc[oo][1][1] = fmaf(v[1][2], wo[2 * 4 + 0], acc[oo][1][1]);
      acc[oo][1][1] = fmaf(v[2][1], wo[0 * 4 + 2], acc[oo][1][1]);
      acc[oo][1][1] = fmaf(v[2][2], wo[0 * 4 + 0], acc[oo][1][1]);
    }
  }
  float* ob = out + n * 5184 + (2 * iy) * 18 + 2 * ix;
#pragma unroll
  for (int oo = 0; oo < 4; ++oo) {
    int o = og * 4 + oo;
    float s = g[o] / sqrtf(bv[o] + BN_EPS);
    float sh = bb[o] - bm[o] * s;
    float bo = bias[o];
    float r00 = fmaxf((acc[oo][0][0] + bo) * s + sh, 0.0f);
    float r01 = fmaxf((acc[oo][0][1] + bo) * s + sh, 0.0f);
    float r10 = fmaxf((acc[oo][1][0] + bo) * s + sh, 0.0f);
    float r11 = fmaxf((acc[oo][1][1] + bo) * s + sh, 0.0f);
    float* op = ob + o * 324;
    *(float2*)&op[0]  = make_float2(r00, r01);
    *(float2*)&op[18] = make_float2(r10, r11);
  }
}

// dw3: convT 16->16 k2 s2 p1, 18->34. INPUT-STATIONARY.
__global__ void k_dw3(const float* __restrict__ in, const float* __restrict__ w,
                      const float* __restrict__ bias,
                      const float* __restrict__ g, const float* __restrict__ bb,
                      const float* __restrict__ bm, const float* __restrict__ bv,
                      float* __restrict__ out) {
  int t = blockIdx.x * 256 + threadIdx.x;   // 165888 total
  int ii = t % 324; int n = t / 324;
  int iy = ii / 18, ix = ii % 18;
  const float* ib = in + n * 5184 + iy * 18 + ix;
  float acc[4][16];
#pragma unroll
  for (int a = 0; a < 4; ++a)
#pragma unroll
    for (int o = 0; o < 16; ++o) acc[a][o] = 0.0f;
  for (int i = 0; i < 16; ++i) {
    float v = ib[i * 324];
    const float4* wr = (const float4*)(w + i * 64);
#pragma unroll
    for (int o = 0; o < 16; ++o) {
      float4 wt = wr[o];
      acc[0][o] = fmaf(v, wt.x, acc[0][o]);
      acc[1][o] = fmaf(v, wt.y, acc[1][o]);
      acc[2][o] = fmaf(v, wt.z, acc[2][o]);
      acc[3][o] = fmaf(v, wt.w, acc[3][o]);
    }
  }
  int yo0 = 2 * iy - 1, xo0 = 2 * ix - 1;
  float* ob = out + n * 18496;
#pragma unroll
  for (int o = 0; o < 16; ++o) {
    float s = g[o] / sqrtf(bv[o] + BN_EPS);
    float sh = bb[o] - bm[o] * s;
    float bo = bias[o];
#pragma unroll
    for (int a = 0; a < 2; ++a)
#pragma unroll
      for (int b = 0; b < 2; ++b) {
        int yo = yo0 + a, xo = xo0 + b;
        if (yo >= 0 && yo < 34 && xo >= 0 && xo < 34)
          ob[o * 1156 + yo * 34 + xo] = fmaxf((acc[a * 2 + b][o] + bo) * s + sh, 0.0f);
      }
  }
}

// dw4 (k2 s2 p0, 34->68) + bn + relu + ow + ob, INPUT-STATIONARY fused.
__global__ void k_dw4ow(const float* __restrict__ in, const float* __restrict__ w,
                        const float* __restrict__ bias,
                        const float* __restrict__ g, const float* __restrict__ bb,
                        const float* __restrict__ bm, const float* __restrict__ bv,
                        const float* __restrict__ oww, const float* __restrict__ obb,
                        float* __restrict__ out) {
  int t = blockIdx.x * 256 + threadIdx.x;   // 591872 total
  int ii = t % 1156; int n = t / 1156;
  int iy = ii / 34, ix = ii % 34;
  const float* ib = in + n * 18496 + iy * 34 + ix;
  float acc[4][16];
#pragma unroll
  for (int a = 0; a < 4; ++a)
#pragma unroll
    for (int o = 0; o < 16; ++o) acc[a][o] = 0.0f;
  for (int i = 0; i < 16; ++i) {
    float v = ib[i * 1156];
    const float4* wr = (const float4*)(w + i * 64);
#pragma unroll
    for (int o = 0; o < 16; ++o) {
      float4 wt = wr[o];
      acc[0][o] = fmaf(v, wt.x, acc[0][o]);
      acc[1][o] = fmaf(v, wt.y, acc[1][o]);
      acc[2][o] = fmaf(v, wt.z, acc[2][o]);
      acc[3][o] = fmaf(v, wt.w, acc[3][o]);
    }
  }
  float r[4];
#pragma unroll
  for (int a = 0; a < 4; ++a) r[a] = obb[0];
#pragma unroll
  for (int o = 0; o < 16; ++o) {
    float s = g[o] / sqrtf(bv[o] + BN_EPS);
    float sh = bb[o] - bm[o] * s;
    float bo = bias[o];
    float wo = oww[o];
#pragma unroll
    for (int a = 0; a < 4; ++a)
      r[a] += fmaxf((acc[a][o] + bo) * s + sh, 0.0f) * wo;
  }
  float* ob = out + n * 4624 + 2 * ix;
  *(float2*)&ob[(2 * iy) * 68]     = make_float2(r[0], r[1]);
  *(float2*)&ob[(2 * iy + 1) * 68] = make_float2(r[2], r[3]);
}

extern "C" void kernel_launch(void* const* d_in, const int* in_sizes, int n_in,
                              void* d_out, int out_size, void* d_ws, size_t ws_size,
                              hipStream_t stream) {
  const float* x     = (const float*)d_in[0];
  const float* ew1   = (const float*)d_in[1];
  const float* eb1   = (const float*)d_in[2];
  const float* ew2   = (const float*)d_in[3];
  const float* eb2   = (const float*)d_in[4];
  const float* ew3   = (const float*)d_in[5];
  const float* eb3   = (const float*)d_in[6];
  const float* ew4   = (const float*)d_in[7];
  const float* eb4   = (const float*)d_in[8];
  const float* fc21w = (const float*)d_in[9];
  const float* fc21b = (const float*)d_in[10];
  const float* fc22w = (const float*)d_in[11];
  const float* fc22b = (const float*)d_in[12];
  const float* fc3w  = (const float*)d_in[13];
  const float* fc3b  = (const float*)d_in[14];
  const float* cw1   = (const float*)d_in[15];
  const float* cb1   = (const float*)d_in[16];
  const float* cw2   = (const float*)d_in[17];
  const float* cb2   = (const float*)d_in[18];
  const float* dw1   = (const float*)d_in[19];
  const float* db1   = (const float*)d_in[20];
  const float* dw2   = (const float*)d_in[21];
  const float* db2   = (const float*)d_in[22];
  const float* dw3   = (const float*)d_in[23];
  const float* db3   = (const float*)d_in[24];
  const float* dw4   = (const float*)d_in[25];
  const float* db4   = (const float*)d_in[26];
  const float* oww   = (const float*)d_in[27];
  const float* obb   = (const float*)d_in[28];
  const float* bn1g  = (const float*)d_in[29];
  const float* bn1b  = (const float*)d_in[30];
  const float* bn1m  = (const float*)d_in[31];
  const float* bn1v  = (const float*)d_in[32];
  const float* bn2g  = (const float*)d_in[33];
  const float* bn2b  = (const float*)d_in[34];
  const float* bn2m  = (const float*)d_in[35];
  const float* bn2v  = (const float*)d_in[36];
  const float* bn3g  = (const float*)d_in[37];
  const float* bn3b  = (const float*)d_in[38];
  const float* bn3m  = (const float*)d_in[39];
  const float* bn3v  = (const float*)d_in[40];
  const float* bn4g  = (const float*)d_in[41];
  const float* bn4b  = (const float*)d_in[42];
  const float* bn4m  = (const float*)d_in[43];
  const float* bn4v  = (const float*)d_in[44];
  const float* cbn1g = (const float*)d_in[45];
  const float* cbn1b = (const float*)d_in[46];
  const float* cbn1m = (const float*)d_in[47];
  const float* cbn1v = (const float*)d_in[48];
  const float* dbn1g = (const float*)d_in[49];
  const float* dbn1b = (const float*)d_in[50];
  const float* dbn1m = (const float*)d_in[51];
  const float* dbn1v = (const float*)d_in[52];
  const float* dbn2g = (const float*)d_in[53];
  const float* dbn2b = (const float*)d_in[54];
  const float* dbn2m = (const float*)d_in[55];
  const float* dbn2v = (const float*)d_in[56];
  const float* dbn3g = (const float*)d_in[57];
  const float* dbn3b = (const float*)d_in[58];
  const float* dbn3m = (const float*)d_in[59];
  const float* dbn3v = (const float*)d_in[60];
  const float* dbn4g = (const float*)d_in[61];
  const float* dbn4b = (const float*)d_in[62];
  const float* dbn4m = (const float*)d_in[63];
  const float* dbn4v = (const float*)d_in[64];
  const float* emb   = (const float*)d_in[65];

  float* out = (float*)d_out;
  float* xt_o  = out;                 // [512,1,68,68]  2,367,488
  float* z_o   = out + 2367488;       // [512,64]
  float* mu_o  = out + 2400256;       // [512,64]
  float* lv_o  = out + 2433024;       // [512,64]
  float* zex_o = out + 2465792;       // [512,32,9,9]  1,327,104
  float* zqx_o = out + 3792896;       // [512,32,9,9]
  float* lat_o = out + 5120000;       // [512,9,9]

  float* ws = (float*)d_ws;
  // lifetime-based reuse; high-water ~14.12M floats (56.5 MB)
  float* A    = ws;                   // padded NCHW [512,16,34,34] = 9,469,952; conv1->conv2
  float* Bt   = ws + 9469952;         // [512,16,16,16] 2,097,152; conv2->c34
  float* Dhl  = ws;                   // hl [512,10368] 5,308,416; c34->gemm1 (A dead)
  float* part = ws + 9469952;         // 4,194,304; gemm1->fc_red (Bt dead)
  float* Eco  = ws;                   // [512,10368]; fc3->k_cw (Dhl dead)
  float* zt   = ws + 9469952;         // [41472,32] 1,327,104; k_cw->vq2g (part dead)
  float* G    = ws + 10797056;        // [512,16,9,9] 663,552; vq2g->dw2
  float* H    = ws + 11460608;        // [512,16,18,18] 2,654,208; dw2->dw3
  float* I    = ws;                   // [512,16,34,34] 9,469,952; dw3->dw4 (Eco dead)
  float* eev  = ws + 14114816;        // [512]
  float* wr2  = ws + 14115328;        // [4096] reordered conv2 weights

  k_pad0<<<512, 256, 0, stream>>>(A);
  k_wr2<<<16, 256, 0, stream>>>(ew2, wr2);
  k_conv1<<<2048, 256, 0, stream>>>(x, ew1, eb1, bn1g, bn1b, bn1m, bn1v, A);
  k_conv2<<<2048, 256, 0, stream>>>(A, wr2, eb2, bn2g, bn2b, bn2m, bn2v, Bt);
  k_c34<<<1024, 256, 0, stream>>>(Bt, ew3, eb3, bn3g, bn3b, bn3m, bn3v,
                                  ew4, eb4, bn4g, bn4b, bn4m, bn4v, Dhl);
  k_gemm1<<<dim3(64, 8), 256, 0, stream>>>(Dhl, fc21w, fc22w, part);
  k_fc_red<<<256, 256, 0, stream>>>(part, fc21b, fc22b, z_o, mu_o, lv_o);
  k_ee<<<2, 256, 0, stream>>>(emb, eev);
  k_fc3<<<dim3(81, 16), 128, 0, stream>>>(z_o, fc3w, fc3b, Eco);
  k_cw<<<512, 256, 0, stream>>>(Eco, cw1, cb1, cbn1g, cbn1b, cbn1m, cbn1v, cw2, cb2, zex_o, zt);
  k_vq2g<<<648, 256, 0, stream>>>(zt, emb, eev, dw1, db1, dbn1g, dbn1b, dbn1m, dbn1v,
                                  lat_o, zqx_o, G);
  k_dw2<<<648, 256, 0, stream>>>(G, dw2, db2, dbn2g, dbn2b, dbn2m, dbn2v, H);
  k_dw3<<<648, 256, 0, stream>>>(H, dw3, db3, dbn3g, dbn3b, dbn3m, dbn3v, I);
  k_dw4ow<<<2312, 256, 0, stream>>>(I, dw4, db4, dbn4g, dbn4b, dbn4m, dbn4v, oww, obb, xt_o);
}